// Round 8
// baseline (556.238 us; speedup 1.0000x reference)
//
#include <hip/hip_runtime.h>

#define NSEQ   4096
#define TSTEPS 512
#define FIN    5
#define HID    64
#define SPB    8      // sequences per block — 512 blocks -> 2 blocks/CU (TLP)
#define BLK    512    // 8 waves: w0-3 "G" (gate MFMA + dense epilogue), w4-7 "E" (seed + staging)

// Neutral names — do NOT reuse HIP vector-type names like short8 (R4 crash)
typedef __attribute__((ext_vector_type(8))) short bsh8;    // 8 bf16 in 4 VGPRs
typedef __attribute__((ext_vector_type(4))) float f32x4;   // MFMA accumulator
typedef __attribute__((ext_vector_type(4))) int   i32x4;

#define MFMA16(A, B, C) __builtin_amdgcn_mfma_f32_16x16x32_bf16((A), (B), (C), 0, 0, 0)

// Gate pre-scaling folded into weights/biases so MFMA output is exp2-ready.
//   i,f,o rows scaled by -log2e  -> sigmoid = rcp(1 + exp2(m))
//   g rows scaled by +2*log2e    -> tanh    = (Eg-1)/(Eg+1)
//   c tracked as cs = 2*log2e*c  -> tanh(c) = (Ec-1)/(Ec+1)
#define LOG2E 1.4426950408889634f
#define SNEG  (-LOG2E)
#define SPOS  (2.0f * LOG2E)

struct Frag2 { bsh8 hi; bsh8 lo; };

__device__ __forceinline__ unsigned short bf16hi_rn(float x) {
    unsigned u = __float_as_uint(x);
    return (unsigned short)((u + 0x7fffu + ((u >> 16) & 1u)) >> 16);
}
__device__ __forceinline__ void split_bf16(float v, unsigned short& h, unsigned short& l) {
    h = bf16hi_rn(v);
    float hf_ = __uint_as_float(((unsigned)h) << 16);
    l = bf16hi_rn(v - hf_);
}

__device__ __forceinline__ Frag2 load_whh_frag(const float* __restrict__ Whh, int row, int k, float scale) {
    const float* p = Whh + row * HID + k;
    Frag2 r;
#pragma unroll
    for (int j = 0; j < 8; ++j) {
        unsigned short h, l;
        split_bf16(scale * p[j], h, l);
        r.hi[j] = (short)h; r.lo[j] = (short)l;
    }
    return r;
}
__device__ __forceinline__ Frag2 load_wih_frag(const float* __restrict__ Wih,
                                               const float* __restrict__ bih,
                                               const float* __restrict__ bhh,
                                               int row, int quad, float scale) {
    Frag2 r;
#pragma unroll
    for (int j = 0; j < 8; ++j) { r.hi[j] = 0; r.lo[j] = 0; }
    if (quad == 0) {
        unsigned short h, l;
#pragma unroll
        for (int j = 0; j < FIN; ++j) {
            split_bf16(scale * Wih[row * FIN + j], h, l);
            r.hi[j] = (short)h; r.lo[j] = (short)l;
        }
        split_bf16(scale * (bih[row] + bhh[row]), h, l);
        r.hi[FIN] = (short)h; r.lo[FIN] = (short)l;
    }
    return r;
}

// stage one 32-step x chunk (bf16-hi, 1.0 in bias slot) into dst[32][16]
// (cols 0-7 only; cols 8-15 are permanent zero pad) — E-waves (256 thr, 1 item each)
__device__ __forceinline__ void stage_chunk(const float* __restrict__ feat,
                                            bsh8 (*dst)[16],
                                            int seq0, int t0, int tidE) {
    int t2 = tidE >> 3;
    int s  = tidE & 7;
    const float* xp = feat + (size_t)(seq0 + s) * (TSTEPS * FIN) + (t0 + t2) * FIN;
    bsh8 v = {0, 0, 0, 0, 0, 0, 0, 0};
#pragma unroll
    for (int j = 0; j < FIN; ++j) v[j] = (short)bf16hi_rn(xp[j]);
    v[FIN] = (short)0x3F80;   // bf16(1.0) -> bias k-slot
    dst[t2][s] = v;
}

// Two-element exp2-native LSTM cell epilogue with paired rcp:
//   trans = 5 exp2 + 1 rcp per element (12 wave-instrs for 2 elems).
//   rcp pairing: rcp(D0*D1), then 1/D0 = R*D1. cs is c in 2*log2e scale.
__device__ __forceinline__ void epi2(float zi0, float zf0, float zg0, float zo0,
                                     float zi1, float zf1, float zg1, float zo1,
                                     float& cs0, float& cs1, float& h0, float& h1) {
    float Ei0 = __builtin_amdgcn_exp2f(zi0), Ei1 = __builtin_amdgcn_exp2f(zi1);
    float Ef0 = __builtin_amdgcn_exp2f(zf0), Ef1 = __builtin_amdgcn_exp2f(zf1);
    float Eg0 = __builtin_amdgcn_exp2f(zg0), Eg1 = __builtin_amdgcn_exp2f(zg1);
    float P10 = (1.0f + Ei0) * (1.0f + Eg0), Pf0 = 1.0f + Ef0;
    float P11 = (1.0f + Ei1) * (1.0f + Eg1), Pf1 = 1.0f + Ef1;
    float D0 = P10 * Pf0, D1 = P11 * Pf1;
    float Rp = __builtin_amdgcn_rcpf(D0 * D1);
    float n10 = __builtin_fmaf(SPOS, Eg0, -SPOS);
    float n11 = __builtin_fmaf(SPOS, Eg1, -SPOS);
    float m0 = __builtin_fmaf(P10, cs0, n10 * Pf0);
    float m1 = __builtin_fmaf(P11, cs1, n11 * Pf1);
    cs0 = (Rp * D1) * m0;          // sf*cs + SPOS*sig(i)*tanh(g)
    cs1 = (Rp * D0) * m1;
    float Eo0 = __builtin_amdgcn_exp2f(zo0), Eo1 = __builtin_amdgcn_exp2f(zo1);
    float Ec0 = __builtin_amdgcn_exp2f(cs0), Ec1 = __builtin_amdgcn_exp2f(cs1);
    float D20 = (1.0f + Eo0) * (1.0f + Ec0);
    float D21 = (1.0f + Eo1) * (1.0f + Ec1);
    float R2p = __builtin_amdgcn_rcpf(D20 * D21);
    h0 = (Ec0 - 1.0f) * (R2p * D21);   // sig(o)*tanh(c)
    h1 = (Ec1 - 1.0f) * (R2p * D20);
}

// R8 structure: R7 (SPB=8, 2 independent blocks/CU) with the occupancy
// attribute REMOVED. R6's launch_bounds(512,4) and R7's waves_per_eu(4) both
// produced an effective 64-VGPR cap -> ~50 spilled regs -> 24 MB scratch
// traffic on the serial chain (WRITE_SIZE counter). Bare __launch_bounds__(512)
// is the R2-proven configuration: 76 VGPR, zero spill, and 76 <= 128 means
// the 4-waves/SIMD occupancy needed for 2 co-resident blocks happens
// naturally. Everything else identical to R7:
//   - seed rides the MFMA C-input (E stores raw f32x4; 4 ds_read_b128 feed
//     the first MFMA of each gate chain).
//   - acc densified once via __shfl_xor 32 (quads 2,3 take rows {2,3},{6,7});
//     whole epilogue = ONE epi2 = 12 trans instrs/step.
__global__ __launch_bounds__(BLK)
void lstm_kernel(const float* __restrict__ feat,
                 const float* __restrict__ Wih,
                 const float* __restrict__ Whh,
                 const float* __restrict__ bih,
                 const float* __restrict__ bhh,
                 const float* __restrict__ Wd,
                 const float* __restrict__ bd,
                 float* __restrict__ pred,
                 float* __restrict__ accums) {
    __shared__ bsh8  aA[2][16][9];                         // h bf16-hi (rows 8-15 perm. zero)
    __shared__ bsh8  xb[2][32][16];                        // x chunks, cols 8-15 zero pad (16 KB)
    __shared__ __align__(16) f32x4 sg[2][4][4][64];        // raw seed [parity][w][gate][lane] (32 KB)
    __shared__ float hf[SPB][HID + 1];                     // final h fp32
    __shared__ float pf[SPB][17];                          // pred partials

    const int tid   = threadIdx.x;
    const int w     = tid >> 6;
    const int lane  = tid & 63;
    const int col   = lane & 15;       // MFMA col / A-row (seq)
    const int quad  = lane >> 4;
    const int seq0  = blockIdx.x * SPB;

    if (blockIdx.x == 0 && tid < 4) accums[tid] = 0.0f;

    {   // zero aA (both parities; rows 8-15 stay zero forever)
        bsh8 z = {0, 0, 0, 0, 0, 0, 0, 0};
        if (tid < 2 * 16 * 9) (&aA[0][0][0])[tid] = z;
        // zero xb cols 8-15 (both buffers) — staging never touches them
        if (tid < 2 * 32 * 8) {
            int b  = tid >> 8;
            int t2 = (tid >> 3) & 31;
            int s8 = 8 + (tid & 7);
            xb[b][t2][s8] = z;
        }
    }
    if (w >= 4) stage_chunk(feat, xb[0], seq0, 0, tid - 256);

    // lane-dense epilogue row mapping (quads 0..3 -> base rows 0,4,2,6)
    const int rA   = (quad & 1) * 4 + ((quad >> 1) ? 2 : 0);
    const bool loq = (quad < 2);

    if (w < 4) {
        // ---------------- G-waves: h-MFMA (C=seed) + dense epilogue ----------------
        const int u = 16 * w + col;
        const Frag2 b00 = load_whh_frag(Whh, 0*HID + u,      quad*8, SNEG);
        const Frag2 b01 = load_whh_frag(Whh, 0*HID + u, 32 + quad*8, SNEG);
        const Frag2 b10 = load_whh_frag(Whh, 1*HID + u,      quad*8, SNEG);
        const Frag2 b11 = load_whh_frag(Whh, 1*HID + u, 32 + quad*8, SNEG);
        const Frag2 b20 = load_whh_frag(Whh, 2*HID + u,      quad*8, SPOS);
        const Frag2 b21 = load_whh_frag(Whh, 2*HID + u, 32 + quad*8, SPOS);
        const Frag2 b30 = load_whh_frag(Whh, 3*HID + u,      quad*8, SNEG);
        const Frag2 b31 = load_whh_frag(Whh, 3*HID + u, 32 + quad*8, SNEG);

        __syncthreads();   // init + xb[0] staged

        float cs0 = 0.f, cs1 = 0.f;    // c (2*log2e scale) for rows rA, rA+1
        unsigned short* const aAb = (unsigned short*)&aA[0][0][0];
        const int rowbase = rA * 72 + u;       // aA row pitch = 72 shorts
        const int aAhalf  = 16 * 9 * 8;        // shorts per parity buffer
        __builtin_amdgcn_s_setprio(1);         // T5: favor the critical wave

        for (int t = 0; t < TSTEPS; ++t) {
            const int buf = t & 1;
            const int nb  = buf ^ 1;
            __syncthreads();   // h(t-1) + sg[buf] visible

            bsh8 ah0 = aA[buf][col][quad];
            bsh8 ah1 = aA[buf][col][4 + quad];
            f32x4 s0 = sg[buf][w][0][lane];    // C-inputs for the 4 gate chains
            f32x4 s1 = sg[buf][w][1][lane];
            f32x4 s2 = sg[buf][w][2][lane];
            f32x4 s3 = sg[buf][w][3][lane];

            f32x4 acc0 = MFMA16(ah0, b00.hi, s0);
            f32x4 acc1 = MFMA16(ah0, b10.hi, s1);
            f32x4 acc2 = MFMA16(ah0, b20.hi, s2);
            f32x4 acc3 = MFMA16(ah0, b30.hi, s3);
            acc0 = MFMA16(ah1, b01.hi, acc0);
            acc1 = MFMA16(ah1, b11.hi, acc1);
            acc2 = MFMA16(ah1, b21.hi, acc2);
            acc3 = MFMA16(ah1, b31.hi, acc3);
            acc0 = MFMA16(ah0, b00.lo, acc0);
            acc1 = MFMA16(ah0, b10.lo, acc1);
            acc2 = MFMA16(ah0, b20.lo, acc2);
            acc3 = MFMA16(ah0, b30.lo, acc3);
            acc0 = MFMA16(ah1, b01.lo, acc0);
            acc1 = MFMA16(ah1, b11.lo, acc1);
            acc2 = MFMA16(ah1, b21.lo, acc2);
            acc3 = MFMA16(ah1, b31.lo, acc3);

            // dense redistribution: quads 2,3 take rows {2,3},{6,7} from quads 0,1
            float x00 = __shfl_xor(acc0[2], 32, 64), x01 = __shfl_xor(acc0[3], 32, 64);
            float x10 = __shfl_xor(acc1[2], 32, 64), x11 = __shfl_xor(acc1[3], 32, 64);
            float x20 = __shfl_xor(acc2[2], 32, 64), x21 = __shfl_xor(acc2[3], 32, 64);
            float x30 = __shfl_xor(acc3[2], 32, 64), x31 = __shfl_xor(acc3[3], 32, 64);
            float zi0 = loq ? acc0[0] : x00, zi1 = loq ? acc0[1] : x01;
            float zf0 = loq ? acc1[0] : x10, zf1 = loq ? acc1[1] : x11;
            float zg0 = loq ? acc2[0] : x20, zg1 = loq ? acc2[1] : x21;
            float zo0 = loq ? acc3[0] : x30, zo1 = loq ? acc3[1] : x31;

            float h0, h1;
            epi2(zi0, zf0, zg0, zo0, zi1, zf1, zg1, zo1, cs0, cs1, h0, h1);
            unsigned pk;
            asm("v_cvt_pk_bf16_f32 %0, %1, %2" : "=v"(pk) : "v"(h0), "v"(h1));
            unsigned short* hp = aAb + nb * aAhalf + rowbase;
            hp[0]  = (unsigned short)pk;          // row rA
            hp[72] = (unsigned short)(pk >> 16);  // row rA+1
            if (t == TSTEPS - 1) {
                hf[rA + 0][u] = h0;
                hf[rA + 1][u] = h1;
            }
        }
        __builtin_amdgcn_s_setprio(0);
    } else {
        // ---------------- E-waves: x-projection seed + staging ----------------
        const int wE   = w - 4;
        const int tidE = tid - 256;
        const int uE   = 16 * wE + col;
        const Frag2 w0 = load_wih_frag(Wih, bih, bhh, 0*HID + uE, quad, SNEG);
        const Frag2 w1 = load_wih_frag(Wih, bih, bhh, 1*HID + uE, quad, SNEG);
        const Frag2 w2 = load_wih_frag(Wih, bih, bhh, 2*HID + uE, quad, SPOS);
        const Frag2 w3 = load_wih_frag(Wih, bih, bhh, 3*HID + uE, quad, SNEG);

        __syncthreads();   // init + xb[0] staged

        {   // seed(0) -> sg[0] (raw f32x4; before first in-loop barrier)
            bsh8 ax = xb[0][0][col];
            f32x4 e0 = {0.f,0.f,0.f,0.f}, e1 = e0, e2 = e0, e3 = e0;
            e0 = MFMA16(ax, w0.hi, e0); e0 = MFMA16(ax, w0.lo, e0);
            e1 = MFMA16(ax, w1.hi, e1); e1 = MFMA16(ax, w1.lo, e1);
            e2 = MFMA16(ax, w2.hi, e2); e2 = MFMA16(ax, w2.lo, e2);
            e3 = MFMA16(ax, w3.hi, e3); e3 = MFMA16(ax, w3.lo, e3);
            sg[0][wE][0][lane] = e0;
            sg[0][wE][1][lane] = e1;
            sg[0][wE][2][lane] = e2;
            sg[0][wE][3][lane] = e3;
        }
        for (int t = 0; t < TSTEPS; ++t) {
            __syncthreads();   // matches G's per-step barrier
            if ((t & 31) == 0 && t + 32 < TSTEPS)
                stage_chunk(feat, xb[((t >> 5) + 1) & 1], seq0, ((t >> 5) + 1) * 32, tidE);
            if (t + 1 < TSTEPS) {
                const int t1 = t + 1;
                bsh8 ax = xb[(t1 >> 5) & 1][t1 & 31][col];
                f32x4 e0 = {0.f,0.f,0.f,0.f}, e1 = e0, e2 = e0, e3 = e0;
                e0 = MFMA16(ax, w0.hi, e0); e0 = MFMA16(ax, w0.lo, e0);
                e1 = MFMA16(ax, w1.hi, e1); e1 = MFMA16(ax, w1.lo, e1);
                e2 = MFMA16(ax, w2.hi, e2); e2 = MFMA16(ax, w2.lo, e2);
                e3 = MFMA16(ax, w3.hi, e3); e3 = MFMA16(ax, w3.lo, e3);
                const int sb = t1 & 1;
                sg[sb][wE][0][lane] = e0;
                sg[sb][wE][1][lane] = e1;
                sg[sb][wE][2][lane] = e2;
                sg[sb][wE][3][lane] = e3;
            }
        }
    }
    __syncthreads();   // hf visible

    // ---- fused pred head: pred = leaky_relu(h @ Wd^T + bd) ----
    if (tid < 8 * 16) {
        int s  = tid & 7;
        int hq = tid >> 3;           // 16 unit-groups of 4
        int j0 = hq * 4;
        float part = hf[s][j0] * Wd[j0] + hf[s][j0 + 1] * Wd[j0 + 1]
                   + hf[s][j0 + 2] * Wd[j0 + 2] + hf[s][j0 + 3] * Wd[j0 + 3];
        pf[s][hq] = part;
    }
    __syncthreads();
    if (tid < SPB) {
        float sum = bd[0];
#pragma unroll
        for (int j = 0; j < 16; ++j) sum += pf[tid][j];
        float p = (sum >= 0.0f) ? sum : 0.2f * sum;
        pred[seq0 + tid] = p;
    }
}

// fused losses: grid 512 (2 blocks/CU), 8 i-rows per block, f32x4 LDS reads.
// block 0 additionally does the masked-MSE partials.
__global__ __launch_bounds__(256)
void loss_kernel(const float* __restrict__ pred,
                 const float* __restrict__ ret,
                 const int* __restrict__ mask,
                 float* __restrict__ accums) {
    __shared__ __align__(16) float sp[NSEQ];
    __shared__ __align__(16) float sg_[NSEQ];
    __shared__ __align__(16) float sq[NSEQ];
    __shared__ float wsum[8];
    int tid = threadIdx.x;
    for (int idx = tid; idx < NSEQ / 4; idx += 256) {
        f32x4 p4 = ((const f32x4*)pred)[idx];
        f32x4 g4 = ((const f32x4*)ret)[idx];
        i32x4 m4 = ((const i32x4*)mask)[idx];
        f32x4 q4;
#pragma unroll
        for (int l = 0; l < 4; ++l) q4[l] = m4[l] ? 1.0f : 0.0f;
        *(f32x4*)&sp[idx * 4] = p4;
        *(f32x4*)&sg_[idx * 4] = g4;
        *(f32x4*)&sq[idx * 4] = q4;
    }
    __syncthreads();

    if (blockIdx.x == 0) {   // regression loss partials
        float v = 0.0f, m = 0.0f;
        for (int j = tid; j < NSEQ; j += 256) {
            float mj = sq[j];
            float d  = sp[j] - sg_[j];
            v += d * d * mj;
            m += mj;
        }
#pragma unroll
        for (int off = 32; off > 0; off >>= 1) {
            v += __shfl_down(v, off, 64);
            m += __shfl_down(m, off, 64);
        }
        if ((tid & 63) == 0) {
            atomicAdd(&accums[0], v);
            atomicAdd(&accums[1], m);
        }
    }

    int iloc = tid >> 5;          // 8 rows per block
    int jp   = tid & 31;          // 32 lanes per row
    int i    = blockIdx.x * 8 + iloc;
    float pi = sp[i], gi = sg_[i], qi = sq[i];
    float sum = 0.0f;
    for (int j0 = jp * 4; j0 < NSEQ; j0 += 128) {
        f32x4 p4 = *(const f32x4*)&sp[j0];
        f32x4 g4 = *(const f32x4*)&sg_[j0];
        f32x4 q4 = *(const f32x4*)&sq[j0];
#pragma unroll
        for (int l = 0; l < 4; ++l) {
            float t = -(p4[l] - pi) * (g4[l] - gi);
            sum += fmaxf(t, 0.0f) * q4[l];
        }
    }
    sum *= qi;
#pragma unroll
    for (int off = 16; off > 0; off >>= 1) sum += __shfl_down(sum, off, 32);
    if (jp == 0) wsum[iloc] = sum;
    __syncthreads();
    if (tid == 0) {
        float s = wsum[0] + wsum[1] + wsum[2] + wsum[3]
                + wsum[4] + wsum[5] + wsum[6] + wsum[7];
        atomicAdd(&accums[2], s);
    }
}

__global__ void final_kernel(const float* __restrict__ accums,
                             float* __restrict__ out) {
    float reg  = accums[0] / (accums[1] + 1e-8f);
    float rank = accums[2] / 16777216.0f;   // N*N
    out[NSEQ + 0] = reg + rank;
    out[NSEQ + 1] = reg;
    out[NSEQ + 2] = rank;
}

extern "C" void kernel_launch(void* const* d_in, const int* in_sizes, int n_in,
                              void* d_out, int out_size, void* d_ws, size_t ws_size,
                              hipStream_t stream) {
    const float* feat = (const float*)d_in[0];
    const float* ret  = (const float*)d_in[1];
    const int*   mask = (const int*)d_in[2];
    const float* Wih  = (const float*)d_in[3];
    const float* Whh  = (const float*)d_in[4];
    const float* bih  = (const float*)d_in[5];
    const float* bhh  = (const float*)d_in[6];
    const float* Wd   = (const float*)d_in[7];
    const float* bd   = (const float*)d_in[8];
    float* out    = (float*)d_out;
    float* accums = (float*)d_ws;            // [0..3] loss partials

    lstm_kernel<<<NSEQ / SPB, BLK, 0, stream>>>(feat, Wih, Whh, bih, bhh,
                                                Wd, bd, out, accums);
    loss_kernel<<<NSEQ / 8, 256, 0, stream>>>(out, ret, mask, accums);
    final_kernel<<<1, 1, 0, stream>>>(accums, out);
}

// Round 9
// 359.146 us; speedup vs baseline: 1.5488x; 1.5488x over previous
//
#include <hip/hip_runtime.h>

#define NSEQ   4096
#define TSTEPS 512
#define FIN    5
#define HID    64
#define SPB    16     // sequences per block (MFMA M)
#define BLK    512    // 8 waves: w0-3 "G" (gate MFMA + epilogue), w4-7 "E" (x-proj seed + staging)
#define LOSSB  512    // loss grid (8 rows/block)

// Neutral names — do NOT reuse HIP vector-type names like short8 (R4 crash)
typedef __attribute__((ext_vector_type(8))) short bsh8;    // 8 bf16 in 4 VGPRs
typedef __attribute__((ext_vector_type(4))) float f32x4;   // MFMA accumulator
typedef __attribute__((ext_vector_type(4))) int   i32x4;

#define MFMA16(A, B, C) __builtin_amdgcn_mfma_f32_16x16x32_bf16((A), (B), (C), 0, 0, 0)

// Gate pre-scaling folded into weights/biases so MFMA output is exp2-ready.
//   i,f,o rows scaled by -log2e  -> sigmoid = rcp(1 + exp2(m))
//   g rows scaled by +2*log2e    -> tanh    = (Eg-1)/(Eg+1)
//   c tracked as cs = 2*log2e*c  -> tanh(c) = (Ec-1)/(Ec+1)
#define LOG2E 1.4426950408889634f
#define SNEG  (-LOG2E)
#define SPOS  (2.0f * LOG2E)

struct Frag2 { bsh8 hi; bsh8 lo; };

__device__ __forceinline__ unsigned short bf16hi_rn(float x) {
    unsigned u = __float_as_uint(x);
    return (unsigned short)((u + 0x7fffu + ((u >> 16) & 1u)) >> 16);
}
__device__ __forceinline__ void split_bf16(float v, unsigned short& h, unsigned short& l) {
    h = bf16hi_rn(v);
    float hf_ = __uint_as_float(((unsigned)h) << 16);
    l = bf16hi_rn(v - hf_);
}

// Whh B-fragment, SPLIT hi/lo, pre-scaled per gate (scale applied before split)
__device__ __forceinline__ Frag2 load_whh_frag(const float* __restrict__ Whh, int row, int k, float scale) {
    const float* p = Whh + row * HID + k;
    Frag2 r;
#pragma unroll
    for (int j = 0; j < 8; ++j) {
        unsigned short h, l;
        split_bf16(scale * p[j], h, l);
        r.hi[j] = (short)h; r.lo[j] = (short)l;
    }
    return r;
}
// Wih B-fragment with bias folded into k-slot FIN (A carries 1.0 there)
__device__ __forceinline__ Frag2 load_wih_frag(const float* __restrict__ Wih,
                                               const float* __restrict__ bih,
                                               const float* __restrict__ bhh,
                                               int row, int quad, float scale) {
    Frag2 r;
#pragma unroll
    for (int j = 0; j < 8; ++j) { r.hi[j] = 0; r.lo[j] = 0; }
    if (quad == 0) {
        unsigned short h, l;
#pragma unroll
        for (int j = 0; j < FIN; ++j) {
            split_bf16(scale * Wih[row * FIN + j], h, l);
            r.hi[j] = (short)h; r.lo[j] = (short)l;
        }
        split_bf16(scale * (bih[row] + bhh[row]), h, l);
        r.hi[FIN] = (short)h; r.lo[FIN] = (short)l;
    }
    return r;
}

// stage one 64-step x chunk (bf16-hi, 1.0 in bias slot) into dst[64][SPB] — E-waves (256 thr)
__device__ __forceinline__ void stage_chunk(const float* __restrict__ feat,
                                            bsh8 (*dst)[SPB],
                                            int seq0, int t0, int tidE) {
#pragma unroll
    for (int it = 0; it < (64 * SPB) / 256; ++it) {
        int idx = tidE + it * 256;
        int t2  = idx >> 4;
        int s   = idx & 15;
        const float* xp = feat + (size_t)(seq0 + s) * (TSTEPS * FIN) + (t0 + t2) * FIN;
        bsh8 v = {0, 0, 0, 0, 0, 0, 0, 0};
#pragma unroll
        for (int j = 0; j < FIN; ++j) v[j] = (short)bf16hi_rn(xp[j]);
        v[FIN] = (short)0x3F80;   // bf16(1.0) -> bias k-slot
        dst[t2][s] = v;
    }
}

// Two-element exp2-native LSTM cell epilogue with paired rcp:
//   trans = 5 exp2 + 1 rcp per element (12 wave-instrs for 2 elems).
//   rcp pairing: rcp(D0*D1), then 1/D0 = R*D1. cs is c in 2*log2e scale.
__device__ __forceinline__ void epi2(float zi0, float zf0, float zg0, float zo0,
                                     float zi1, float zf1, float zg1, float zo1,
                                     float& cs0, float& cs1, float& h0, float& h1) {
    float Ei0 = __builtin_amdgcn_exp2f(zi0), Ei1 = __builtin_amdgcn_exp2f(zi1);
    float Ef0 = __builtin_amdgcn_exp2f(zf0), Ef1 = __builtin_amdgcn_exp2f(zf1);
    float Eg0 = __builtin_amdgcn_exp2f(zg0), Eg1 = __builtin_amdgcn_exp2f(zg1);
    float P10 = (1.0f + Ei0) * (1.0f + Eg0), Pf0 = 1.0f + Ef0;
    float P11 = (1.0f + Ei1) * (1.0f + Eg1), Pf1 = 1.0f + Ef1;
    float D0 = P10 * Pf0, D1 = P11 * Pf1;
    float Rp = __builtin_amdgcn_rcpf(D0 * D1);
    float n10 = __builtin_fmaf(SPOS, Eg0, -SPOS);
    float n11 = __builtin_fmaf(SPOS, Eg1, -SPOS);
    float m0 = __builtin_fmaf(P10, cs0, n10 * Pf0);
    float m1 = __builtin_fmaf(P11, cs1, n11 * Pf1);
    cs0 = (Rp * D1) * m0;          // sf*cs + SPOS*sig(i)*tanh(g)
    cs1 = (Rp * D0) * m1;
    float Eo0 = __builtin_amdgcn_exp2f(zo0), Eo1 = __builtin_amdgcn_exp2f(zo1);
    float Ec0 = __builtin_amdgcn_exp2f(cs0), Ec1 = __builtin_amdgcn_exp2f(cs1);
    float D20 = (1.0f + Eo0) * (1.0f + Ec0);
    float D21 = (1.0f + Eo1) * (1.0f + Ec1);
    float R2p = __builtin_amdgcn_rcpf(D20 * D21);
    h0 = (Ec0 - 1.0f) * (R2p * D21);   // sig(o)*tanh(c)
    h1 = (Ec1 - 1.0f) * (R2p * D20);
}

// R9 structure: R2 (champion, 295 us lstm) + verified micro-opts.
//  - SPB=16, 256 blocks (1/CU), 8 waves: G (w0-3) gate-MFMA + epilogue,
//    E (w4-7) x-proj seed + staging. ONE barrier per step. seedb is the
//    lane-linear conflict-free f32x4 mailbox (R2).
//  - Paired-rcp epi2: 24 trans/step (was 32) — R3+-verified math.
//  - Seed rides the MFMA C-input (R8-verified) — no post-MFMA adds; seed
//    ds_read latency overlaps the ah frag reads.
//  - Depth-2 MFMA chains: per gate, P=(ah0:hi,lo | C=seed) and Q=(ah1:hi,lo)
//    run as two independent 2-deep chains + one f32x4 add (was one 4-deep
//    chain) — cuts ~100 cyc of dependent-MFMA latency per step.
__global__ __launch_bounds__(BLK)
void lstm_kernel(const float* __restrict__ feat,
                 const float* __restrict__ Wih,
                 const float* __restrict__ Whh,
                 const float* __restrict__ bih,
                 const float* __restrict__ bhh,
                 const float* __restrict__ Wd,
                 const float* __restrict__ bd,
                 float* __restrict__ pred,
                 float* __restrict__ accums) {
    __shared__ bsh8  aA[2][SPB][9];                        // h bf16-hi, double-buffered
    __shared__ bsh8  xb[2][64][SPB];                       // x chunks (32 KB, E-only)
    __shared__ __align__(16) f32x4 seedb[2][4][4][64];     // [parity][w][gate][lane] (32 KB)
    __shared__ float hf[SPB][HID + 1];                     // final h fp32
    __shared__ float pf[SPB][17];                          // pred partials

    const int tid   = threadIdx.x;
    const int w     = tid >> 6;
    const int lane  = tid & 63;
    const int col   = lane & 15;       // MFMA col / A-row (seq)
    const int quad  = lane >> 4;
    const int quad4 = quad * 4;
    const int seq0  = blockIdx.x * SPB;

    if (blockIdx.x == 0 && tid < 4) accums[tid] = 0.0f;    // loss accums + ticket

    {
        bsh8 z = {0, 0, 0, 0, 0, 0, 0, 0};
        if (tid < SPB * 9) (&aA[0][0][0])[tid] = z;        // h(-1) = 0
    }
    if (w >= 4) stage_chunk(feat, xb[0], seq0, 0, tid - 256);
    __syncthreads();

    if (w < 4) {
        // ---------------- G-waves: serial LSTM path ----------------
        const int u = 16 * w + col;
        const Frag2 b00 = load_whh_frag(Whh, 0*HID + u,      quad*8, SNEG);
        const Frag2 b01 = load_whh_frag(Whh, 0*HID + u, 32 + quad*8, SNEG);
        const Frag2 b10 = load_whh_frag(Whh, 1*HID + u,      quad*8, SNEG);
        const Frag2 b11 = load_whh_frag(Whh, 1*HID + u, 32 + quad*8, SNEG);
        const Frag2 b20 = load_whh_frag(Whh, 2*HID + u,      quad*8, SPOS);
        const Frag2 b21 = load_whh_frag(Whh, 2*HID + u, 32 + quad*8, SPOS);
        const Frag2 b30 = load_whh_frag(Whh, 3*HID + u,      quad*8, SNEG);
        const Frag2 b31 = load_whh_frag(Whh, 3*HID + u, 32 + quad*8, SNEG);

        float cs0 = 0.f, cs1 = 0.f, cs2 = 0.f, cs3 = 0.f;  // c (2*log2e scale), rows quad4+0..3
        __builtin_amdgcn_s_setprio(1);          // T5: favor the critical wave

        unsigned short* const aAb = (unsigned short*)&aA[0][0][0];
        const int rowbase = quad4 * 72 + u;      // aA row pitch = 72 shorts
        const int aAhalf  = SPB * 9 * 8;         // shorts per aA parity buffer

        for (int t = 0; t < TSTEPS; ++t) {
            const int buf = t & 1;
            const int nb  = buf ^ 1;
            __syncthreads();   // h(t-1) + seedb[buf] visible

            bsh8 ah0 = aA[buf][col][quad];
            bsh8 ah1 = aA[buf][col][4 + quad];
            f32x4 s0 = seedb[buf][w][0][lane];   // C-inputs (x·Wih + b)
            f32x4 s1 = seedb[buf][w][1][lane];
            f32x4 s2 = seedb[buf][w][2][lane];
            f32x4 s3 = seedb[buf][w][3][lane];

            const f32x4 zz = {0.f, 0.f, 0.f, 0.f};
            // depth-2 chains: P = ah0(hi->lo) seeded, Q = ah1(hi->lo)
            f32x4 p0 = MFMA16(ah0, b00.hi, s0);
            f32x4 q0 = MFMA16(ah1, b01.hi, zz);
            f32x4 p1 = MFMA16(ah0, b10.hi, s1);
            f32x4 q1 = MFMA16(ah1, b11.hi, zz);
            f32x4 p2 = MFMA16(ah0, b20.hi, s2);
            f32x4 q2 = MFMA16(ah1, b21.hi, zz);
            f32x4 p3 = MFMA16(ah0, b30.hi, s3);
            f32x4 q3 = MFMA16(ah1, b31.hi, zz);
            p0 = MFMA16(ah0, b00.lo, p0);
            q0 = MFMA16(ah1, b01.lo, q0);
            p1 = MFMA16(ah0, b10.lo, p1);
            q1 = MFMA16(ah1, b11.lo, q1);
            p2 = MFMA16(ah0, b20.lo, p2);
            q2 = MFMA16(ah1, b21.lo, q2);
            p3 = MFMA16(ah0, b30.lo, p3);
            q3 = MFMA16(ah1, b31.lo, q3);
            f32x4 z0 = p0 + q0;
            f32x4 z1 = p1 + q1;
            f32x4 z2 = p2 + q2;
            f32x4 z3 = p3 + q3;

            // C/D layout: col=lane&15 (unit), row=quad*4+r (seq)
            float h0, h1, h2, h3;
            epi2(z0[0], z1[0], z2[0], z3[0], z0[1], z1[1], z2[1], z3[1],
                 cs0, cs1, h0, h1);
            epi2(z0[2], z1[2], z2[2], z3[2], z0[3], z1[3], z2[3], z3[3],
                 cs2, cs3, h2, h3);

            unsigned pk01, pk23;
            asm("v_cvt_pk_bf16_f32 %0, %1, %2" : "=v"(pk01) : "v"(h0), "v"(h1));
            asm("v_cvt_pk_bf16_f32 %0, %1, %2" : "=v"(pk23) : "v"(h2), "v"(h3));
            unsigned short* hp = aAb + nb * aAhalf + rowbase;
            hp[0]   = (unsigned short)pk01;
            hp[72]  = (unsigned short)(pk01 >> 16);
            hp[144] = (unsigned short)pk23;
            hp[216] = (unsigned short)(pk23 >> 16);
            if (t == TSTEPS - 1) {
                hf[quad4 + 0][u] = h0;
                hf[quad4 + 1][u] = h1;
                hf[quad4 + 2][u] = h2;
                hf[quad4 + 3][u] = h3;
            }
        }
        __builtin_amdgcn_s_setprio(0);
    } else {
        // ---------------- E-waves: x-projection seed + staging ----------------
        const int wE   = w - 4;
        const int tidE = tid - 256;
        const int uE   = 16 * wE + col;
        const Frag2 w0 = load_wih_frag(Wih, bih, bhh, 0*HID + uE, quad, SNEG);
        const Frag2 w1 = load_wih_frag(Wih, bih, bhh, 1*HID + uE, quad, SNEG);
        const Frag2 w2 = load_wih_frag(Wih, bih, bhh, 2*HID + uE, quad, SPOS);
        const Frag2 w3 = load_wih_frag(Wih, bih, bhh, 3*HID + uE, quad, SNEG);

        {   // seed(0): after initial barrier (xb[0] staged), before first in-loop barrier
            bsh8 ax = xb[0][0][col];
            f32x4 e0 = {0.f,0.f,0.f,0.f}, e1 = e0, e2 = e0, e3 = e0;
            e0 = MFMA16(ax, w0.hi, e0); e0 = MFMA16(ax, w0.lo, e0);
            e1 = MFMA16(ax, w1.hi, e1); e1 = MFMA16(ax, w1.lo, e1);
            e2 = MFMA16(ax, w2.hi, e2); e2 = MFMA16(ax, w2.lo, e2);
            e3 = MFMA16(ax, w3.hi, e3); e3 = MFMA16(ax, w3.lo, e3);
            seedb[0][wE][0][lane] = e0;
            seedb[0][wE][1][lane] = e1;
            seedb[0][wE][2][lane] = e2;
            seedb[0][wE][3][lane] = e3;
        }
        for (int t = 0; t < TSTEPS; ++t) {
            __syncthreads();   // matches G's per-step barrier
            if ((t & 63) == 0 && t + 64 < TSTEPS)
                stage_chunk(feat, xb[((t >> 6) + 1) & 1], seq0, ((t >> 6) + 1) * 64, tidE);
            if (t + 1 < TSTEPS) {
                const int t1 = t + 1;
                bsh8 ax = xb[(t1 >> 6) & 1][t1 & 63][col];
                f32x4 e0 = {0.f,0.f,0.f,0.f}, e1 = e0, e2 = e0, e3 = e0;
                e0 = MFMA16(ax, w0.hi, e0); e0 = MFMA16(ax, w0.lo, e0);
                e1 = MFMA16(ax, w1.hi, e1); e1 = MFMA16(ax, w1.lo, e1);
                e2 = MFMA16(ax, w2.hi, e2); e2 = MFMA16(ax, w2.lo, e2);
                e3 = MFMA16(ax, w3.hi, e3); e3 = MFMA16(ax, w3.lo, e3);
                const int sb = t1 & 1;
                seedb[sb][wE][0][lane] = e0;
                seedb[sb][wE][1][lane] = e1;
                seedb[sb][wE][2][lane] = e2;
                seedb[sb][wE][3][lane] = e3;
            }
        }
    }
    __syncthreads();   // hf visible; E done

    // ---- fused pred head: pred = leaky_relu(h @ Wd^T + bd) ----
    if (tid < 256) {
        int s  = tid & 15;
        int hq = tid >> 4;           // 16 unit-groups of 4
        int j0 = hq * 4;
        float part = hf[s][j0] * Wd[j0] + hf[s][j0 + 1] * Wd[j0 + 1]
                   + hf[s][j0 + 2] * Wd[j0 + 2] + hf[s][j0 + 3] * Wd[j0 + 3];
        pf[s][hq] = part;
    }
    __syncthreads();
    if (tid < SPB) {
        float sum = bd[0];
#pragma unroll
        for (int j = 0; j < 16; ++j) sum += pf[tid][j];
        float p = (sum >= 0.0f) ? sum : 0.2f * sum;
        pred[seq0 + tid] = p;
    }
}

// fused losses: grid 512 (2 blocks/CU), 8 i-rows per block, f32x4 LDS reads.
// block 0 additionally does the masked-MSE partials. The LAST block to finish
// (device-scope ticket in accums[3]) computes the final scalars — final_kernel
// launch eliminated.
__global__ __launch_bounds__(256)
void loss_kernel(const float* __restrict__ pred,
                 const float* __restrict__ ret,
                 const int* __restrict__ mask,
                 float* __restrict__ accums,
                 float* __restrict__ out) {
    __shared__ __align__(16) float sp[NSEQ];
    __shared__ __align__(16) float sg_[NSEQ];
    __shared__ __align__(16) float sq[NSEQ];
    __shared__ float wsum[8];
    int tid = threadIdx.x;
    for (int idx = tid; idx < NSEQ / 4; idx += 256) {
        f32x4 p4 = ((const f32x4*)pred)[idx];
        f32x4 g4 = ((const f32x4*)ret)[idx];
        i32x4 m4 = ((const i32x4*)mask)[idx];
        f32x4 q4;
#pragma unroll
        for (int l = 0; l < 4; ++l) q4[l] = m4[l] ? 1.0f : 0.0f;
        *(f32x4*)&sp[idx * 4] = p4;
        *(f32x4*)&sg_[idx * 4] = g4;
        *(f32x4*)&sq[idx * 4] = q4;
    }
    __syncthreads();

    if (blockIdx.x == 0) {   // regression loss partials
        float v = 0.0f, m = 0.0f;
        for (int j = tid; j < NSEQ; j += 256) {
            float mj = sq[j];
            float d  = sp[j] - sg_[j];
            v += d * d * mj;
            m += mj;
        }
#pragma unroll
        for (int off = 32; off > 0; off >>= 1) {
            v += __shfl_down(v, off, 64);
            m += __shfl_down(m, off, 64);
        }
        if ((tid & 63) == 0) {
            atomicAdd(&accums[0], v);
            atomicAdd(&accums[1], m);
        }
    }

    int iloc = tid >> 5;          // 8 rows per block
    int jp   = tid & 31;          // 32 lanes per row
    int i    = blockIdx.x * 8 + iloc;
    float pi = sp[i], gi = sg_[i], qi = sq[i];
    float sum = 0.0f;
    for (int j0 = jp * 4; j0 < NSEQ; j0 += 128) {
        f32x4 p4 = *(const f32x4*)&sp[j0];
        f32x4 g4 = *(const f32x4*)&sg_[j0];
        f32x4 q4 = *(const f32x4*)&sq[j0];
#pragma unroll
        for (int l = 0; l < 4; ++l) {
            float t = -(p4[l] - pi) * (g4[l] - gi);
            sum += fmaxf(t, 0.0f) * q4[l];
        }
    }
    sum *= qi;
#pragma unroll
    for (int off = 16; off > 0; off >>= 1) sum += __shfl_down(sum, off, 32);
    if (jp == 0) wsum[iloc] = sum;
    __syncthreads();
    if (tid == 0) {
        float s = wsum[0] + wsum[1] + wsum[2] + wsum[3]
                + wsum[4] + wsum[5] + wsum[6] + wsum[7];
        atomicAdd(&accums[2], s);
        __threadfence();                         // make this block's adds visible
        float old = atomicAdd(&accums[3], 1.0f); // device-scope ticket
        if (old == (float)(LOSSB - 1)) {         // last block finalizes
            float a0 = atomicAdd(&accums[0], 0.0f);   // coherent reads
            float a1 = atomicAdd(&accums[1], 0.0f);
            float a2 = atomicAdd(&accums[2], 0.0f);
            float reg  = a0 / (a1 + 1e-8f);
            float rank = a2 / 16777216.0f;            // N*N
            out[NSEQ + 0] = reg + rank;
            out[NSEQ + 1] = reg;
            out[NSEQ + 2] = rank;
        }
    }
}

extern "C" void kernel_launch(void* const* d_in, const int* in_sizes, int n_in,
                              void* d_out, int out_size, void* d_ws, size_t ws_size,
                              hipStream_t stream) {
    const float* feat = (const float*)d_in[0];
    const float* ret  = (const float*)d_in[1];
    const int*   mask = (const int*)d_in[2];
    const float* Wih  = (const float*)d_in[3];
    const float* Whh  = (const float*)d_in[4];
    const float* bih  = (const float*)d_in[5];
    const float* bhh  = (const float*)d_in[6];
    const float* Wd   = (const float*)d_in[7];
    const float* bd   = (const float*)d_in[8];
    float* out    = (float*)d_out;
    float* accums = (float*)d_ws;            // [0..2] loss partials, [3] ticket

    lstm_kernel<<<NSEQ / SPB, BLK, 0, stream>>>(feat, Wih, Whh, bih, bhh,
                                                Wd, bd, out, accums);
    loss_kernel<<<LOSSB, 256, 0, stream>>>(out, ret, mask, accums, out);
}